// Round 11
// baseline (229.696 us; speedup 1.0000x reference)
//
#include <hip/hip_runtime.h>
#include <hip/hip_bf16.h>
#include <hip/hip_fp16.h>

// SJLT projection: out[b, idx[d,c]] += x[b,d] * (2*sign[d,c]-1)
// B=64, D=262144, C=4, P=4096
//
// R11. R10 post-mortem: k_scan 59us = ~69 cyc/pair-op, 25x above issue
// floor -> the hist plain-RMW chain (ds_read -> 120cy -> add -> ds_write,
// un-hoistable due to aliasing) serializes each pair-op. Changes:
//   1. hist RMW -> ds_pk_add_f16 via unsafeAtomicAdd(__half2*): fire-and-
//      forget, no read latency, no collision branch/shfl. Deterministic:
//      hist is wave-private, per-wave LDS ops are in program order.
//      (R2/R3's 339us atomic wall was 64-lane SCATTERED; this pattern is
//      2 contiguous 128B rows = 2-way bank aliasing = free.)
//   2. 8 gathers in flight (16 queue entries per iter).
//   3. k_reduce: uint2 loads + register float4 accum (was scalar __half).
//   4. k_transpose: float4 reads, packed-dword fully-coalesced writes.

constexpr int B_DIM = 64;
constexpr int D_DIM = 262144;
constexpr int P_DIM = 4096;

constexpr int PR_W   = 64;               // p-slots per wave
constexpr int NPR    = P_DIM / PR_W;     // 64 p-ranges
constexpr int NDS    = 64;               // d-slices
constexpr int SLICE  = D_DIM / NDS;      // 4096
constexpr int WPB    = 8;                // waves per block (= pranges per block)
constexpr int SUB    = SLICE / WPB;      // 512 d scanned per wave
constexpr int SCAN_BLOCKS = (NPR / WPB) * NDS;  // 512
constexpr int QCAP   = 96;               // per (target,scanner): mean 32, sd 5.6

// ---- ws layout ----
constexpr size_t PK_OFF   = 0;
constexpr size_t PK_BYTES = (size_t)D_DIM * 4 * sizeof(unsigned short);          // 2 MB
constexpr size_t XT_OFF   = PK_OFF + PK_BYTES;
constexpr size_t XT_BYTES = (size_t)D_DIM * B_DIM * sizeof(unsigned short);      // 33.5 MB
constexpr size_t PART_OFF = XT_OFF + XT_BYTES;
constexpr size_t PART_BYTES = (size_t)NPR * NDS * PR_W * B_DIM * sizeof(__half); // 33.5 MB
constexpr size_t WS_NEED  = PART_OFF + PART_BYTES;                               // ~69 MB

// ---------------- K1: pack idx+sign into ushort ----------------
__global__ __launch_bounds__(256) void k_pack(
    const int* __restrict__ idx, const int* __restrict__ sgn,
    unsigned short* __restrict__ pk) {
    const int d = blockIdx.x * 256 + threadIdx.x;
    const int4 iv = reinterpret_cast<const int4*>(idx)[d];
    const int4 sv = reinterpret_cast<const int4*>(sgn)[d];
    ushort4 o;
    o.x = (unsigned short)((iv.x & 4095) | (sv.x << 15));
    o.y = (unsigned short)((iv.y & 4095) | (sv.y << 15));
    o.z = (unsigned short)((iv.z & 4095) | (sv.z << 15));
    o.w = (unsigned short)((iv.w & 4095) | (sv.w << 15));
    reinterpret_cast<ushort4*>(pk)[d] = o;
}

// ---------------- K2: transpose x[64][D] -> xTb[D][64] (bf16) ----------------
__device__ __forceinline__ unsigned short f32_to_bf16_rne(float f) {
    unsigned u = __float_as_uint(f);
    u += 0x7FFFu + ((u >> 16) & 1u);
    return (unsigned short)(u >> 16);
}

constexpr int TD = 128;   // d's per transpose block
__global__ __launch_bounds__(256) void k_transpose(
    const float* __restrict__ x, unsigned short* __restrict__ xTb) {
    __shared__ unsigned short tile[TD][72];   // 72 stride: ~2-4 way banks max
    const int d0 = blockIdx.x * TD;
    const int t = threadIdx.x;

    #pragma unroll
    for (int i = 0; i < 8; ++i) {
        const int flat = i * 256 + t;          // 0..2047
        const int b    = flat >> 5;            // 0..63
        const int c4   = flat & 31;            // float4 column
        const float4 v = *reinterpret_cast<const float4*>(
            x + (size_t)b * D_DIM + d0 + c4 * 4);
        tile[c4 * 4 + 0][b] = f32_to_bf16_rne(v.x);
        tile[c4 * 4 + 1][b] = f32_to_bf16_rne(v.y);
        tile[c4 * 4 + 2][b] = f32_to_bf16_rne(v.z);
        tile[c4 * 4 + 3][b] = f32_to_bf16_rne(v.w);
    }
    __syncthreads();

    unsigned* dst = reinterpret_cast<unsigned*>(xTb) + (size_t)d0 * 32;
    #pragma unroll
    for (int j = 0; j < 16; ++j) {
        const int dw = j * 256 + t;            // 0..4095
        const int d  = dw >> 5, wv = dw & 31;
        const unsigned* row = reinterpret_cast<const unsigned*>(&tile[d][0]);
        dst[dw] = row[wv];                     // 2 packed bf16 (b=2wv, 2wv+1)
    }
}

// ---------------- K3: 8-wave cooperative scan + atomic-pk process ----------
// u16 entry: bits 0-8 = dloc (scanner-local), 9-14 = poff, 15 = (sv ^ 1).
__global__ __launch_bounds__(WPB * 64, 4) void k_scan(
    const unsigned short* __restrict__ pk,
    const unsigned short* __restrict__ xTb,
    __half* __restrict__ part) {
    __shared__ __half2 hist[WPB][PR_W * 32];                    // 8 x 8 KB = 64 KB
    __shared__ alignas(16) unsigned short q[WPB][WPB][QCAP];    // 12 KB
    __shared__ int qcnt[WPB][WPB];                              // 256 B

    const int w    = threadIdx.x >> 6;
    const int lane = threadIdx.x & 63;
    const int dslice  = blockIdx.x & (NDS - 1);   // stride-64 peers -> same XCD
    const int prgroup = blockIdx.x >> 6;          // 0..7
    const unsigned p0 = (unsigned)(prgroup * (WPB * PR_W));  // 512-wide p base
    const int dbase   = dslice * SLICE;

    __half2* h2 = hist[w];
    {
        unsigned* h32 = reinterpret_cast<unsigned*>(h2);
        #pragma unroll
        for (int k = 0; k < 32; ++k) h32[k * 64 + lane] = 0u;
    }

    // --- scan: wave w scans slice-local d in [w*SUB, (w+1)*SUB) ---
    const ushort4* pk4 = reinterpret_cast<const ushort4*>(pk);
    const unsigned long long lmask = (1ull << lane) - 1ull;
    int c0 = 0, c1 = 0, c2 = 0, c3 = 0, c4 = 0, c5 = 0, c6 = 0, c7 = 0;
    for (int step = 0; step < SUB / 64; ++step) {   // 8 steps
        const int dloc = step * 64 + lane;          // scanner-local (0..511)
        const ushort4 v = pk4[dbase + w * SUB + dloc];
        #pragma unroll
        for (int c = 0; c < 4; ++c) {
            const unsigned u = (c == 0) ? v.x : (c == 1) ? v.y : (c == 2) ? v.z : v.w;
            const unsigned off = (u & 4095u) - p0;            // unsigned wrap
            const bool hit = off < (unsigned)(WPB * PR_W);    // < 512
            const unsigned t = hit ? (off >> 6) : 0xFFu;      // target wave 0..7
            const unsigned long long m0 = __ballot(t == 0u);
            const unsigned long long m1 = __ballot(t == 1u);
            const unsigned long long m2 = __ballot(t == 2u);
            const unsigned long long m3 = __ballot(t == 3u);
            const unsigned long long m4 = __ballot(t == 4u);
            const unsigned long long m5 = __ballot(t == 5u);
            const unsigned long long m6 = __ballot(t == 6u);
            const unsigned long long m7 = __ballot(t == 7u);
            if (hit) {
                const unsigned long long mt =
                    t < 4u ? (t < 2u ? (t == 0u ? m0 : m1) : (t == 2u ? m2 : m3))
                           : (t < 6u ? (t == 4u ? m4 : m5) : (t == 6u ? m6 : m7));
                const int base =
                    t < 4u ? (t < 2u ? (t == 0u ? c0 : c1) : (t == 2u ? c2 : c3))
                           : (t < 6u ? (t == 4u ? c4 : c5) : (t == 6u ? c6 : c7));
                const int pos = base + __popcll(mt & lmask);
                const unsigned e16 = (unsigned)dloc | ((off & 63u) << 9)
                                   | (((u >> 15) ^ 1u) << 15);
                if (pos < QCAP) q[t][w][pos] = (unsigned short)e16;
            }
            c0 += __popcll(m0); c1 += __popcll(m1);
            c2 += __popcll(m2); c3 += __popcll(m3);
            c4 += __popcll(m4); c5 += __popcll(m5);
            c6 += __popcll(m6); c7 += __popcll(m7);
        }
    }
    if (lane == 0) {
        qcnt[0][w] = c0 < QCAP ? c0 : QCAP;
        qcnt[1][w] = c1 < QCAP ? c1 : QCAP;
        qcnt[2][w] = c2 < QCAP ? c2 : QCAP;
        qcnt[3][w] = c3 < QCAP ? c3 : QCAP;
        qcnt[4][w] = c4 < QCAP ? c4 : QCAP;
        qcnt[5][w] = c5 < QCAP ? c5 : QCAP;
        qcnt[6][w] = c6 < QCAP ? c6 : QCAP;
        qcnt[7][w] = c7 < QCAP ? c7 : QCAP;
    }
    __syncthreads();

    // --- process: wave w owns prange = prgroup*8 + w ---
    const char* xs_c = reinterpret_cast<const char*>(xTb + (size_t)dbase * B_DIM);
    const unsigned li4 = (unsigned)(lane & 31) * 4u;
    const bool hi = lane >= 32;

    // pair-op: wrd packs 2 entries (lo16 -> lanes 0-31, hi16 -> lanes 32-63);
    // dv = this lane's gathered dword (2 bf16). Fire-and-forget pk-f16 atomic.
    auto pair_atomic = [&](unsigned wrd, unsigned dv) {
        const unsigned poL = (wrd >> 9) & 63u, poH = (wrd >> 25) & 63u;
        const unsigned smL = (wrd & 0x8000u)     ? 0x80008000u : 0u;
        const unsigned smH = (wrd & 0x80000000u) ? 0x80008000u : 0u;
        const float flo = __uint_as_float(dv << 16);
        const float fhh = __uint_as_float(dv & 0xFFFF0000u);
        unsigned pkb = __builtin_bit_cast(unsigned, __floats2half2_rn(flo, fhh));
        pkb ^= hi ? smH : smL;
        const unsigned a = (hi ? poH : poL) * 32u + (unsigned)(lane & 31);
        unsafeAtomicAdd(&h2[a], __builtin_bit_cast(__half2, pkb));
    };

    for (int s = 0; s < WPB; ++s) {
        const int n = qcnt[w][s];
        const unsigned short* qs = q[w][s];
        const unsigned sb = (unsigned)(s * SUB) * 128u;   // scanner byte base
        int i = 0;
        for (; i + 16 <= n; i += 16) {          // 8 pair-ops, 8 gathers in flight
            const uint4 Ea = *reinterpret_cast<const uint4*>(qs + i);
            const uint4 Eb = *reinterpret_cast<const uint4*>(qs + i + 8);
            const unsigned w0 = __builtin_amdgcn_readfirstlane(Ea.x);
            const unsigned w1 = __builtin_amdgcn_readfirstlane(Ea.y);
            const unsigned w2 = __builtin_amdgcn_readfirstlane(Ea.z);
            const unsigned w3 = __builtin_amdgcn_readfirstlane(Ea.w);
            const unsigned w4 = __builtin_amdgcn_readfirstlane(Eb.x);
            const unsigned w5 = __builtin_amdgcn_readfirstlane(Eb.y);
            const unsigned w6 = __builtin_amdgcn_readfirstlane(Eb.z);
            const unsigned w7 = __builtin_amdgcn_readfirstlane(Eb.w);
            const unsigned va0 = sb + (hi ? ((w0 >> 16) & 511u) : (w0 & 511u)) * 128u + li4;
            const unsigned va1 = sb + (hi ? ((w1 >> 16) & 511u) : (w1 & 511u)) * 128u + li4;
            const unsigned va2 = sb + (hi ? ((w2 >> 16) & 511u) : (w2 & 511u)) * 128u + li4;
            const unsigned va3 = sb + (hi ? ((w3 >> 16) & 511u) : (w3 & 511u)) * 128u + li4;
            const unsigned va4 = sb + (hi ? ((w4 >> 16) & 511u) : (w4 & 511u)) * 128u + li4;
            const unsigned va5 = sb + (hi ? ((w5 >> 16) & 511u) : (w5 & 511u)) * 128u + li4;
            const unsigned va6 = sb + (hi ? ((w6 >> 16) & 511u) : (w6 & 511u)) * 128u + li4;
            const unsigned va7 = sb + (hi ? ((w7 >> 16) & 511u) : (w7 & 511u)) * 128u + li4;
            const unsigned d0 = *reinterpret_cast<const unsigned*>(xs_c + va0);
            const unsigned d1 = *reinterpret_cast<const unsigned*>(xs_c + va1);
            const unsigned d2 = *reinterpret_cast<const unsigned*>(xs_c + va2);
            const unsigned d3 = *reinterpret_cast<const unsigned*>(xs_c + va3);
            const unsigned d4 = *reinterpret_cast<const unsigned*>(xs_c + va4);
            const unsigned d5 = *reinterpret_cast<const unsigned*>(xs_c + va5);
            const unsigned d6 = *reinterpret_cast<const unsigned*>(xs_c + va6);
            const unsigned d7 = *reinterpret_cast<const unsigned*>(xs_c + va7);
            pair_atomic(w0, d0); pair_atomic(w1, d1);
            pair_atomic(w2, d2); pair_atomic(w3, d3);
            pair_atomic(w4, d4); pair_atomic(w5, d5);
            pair_atomic(w6, d6); pair_atomic(w7, d7);
        }
        for (; i + 2 <= n; i += 2) {
            const unsigned wrd = __builtin_amdgcn_readfirstlane(
                *reinterpret_cast<const unsigned*>(qs + i));
            const unsigned va = sb + (hi ? ((wrd >> 16) & 511u) : (wrd & 511u)) * 128u + li4;
            const unsigned dv = *reinterpret_cast<const unsigned*>(xs_c + va);
            pair_atomic(wrd, dv);
        }
        if (i < n) {                            // odd tail: half-wave op
            const unsigned e0 = __builtin_amdgcn_readfirstlane((unsigned)qs[i]);
            if (!hi) {
                const unsigned va = sb + (e0 & 511u) * 128u + li4;
                const unsigned dv = *reinterpret_cast<const unsigned*>(xs_c + va);
                const float flo = __uint_as_float(dv << 16);
                const float fhh = __uint_as_float(dv & 0xFFFF0000u);
                unsigned pkb = __builtin_bit_cast(unsigned, __floats2half2_rn(flo, fhh));
                pkb ^= (e0 & 0x8000u) ? 0x80008000u : 0u;
                const unsigned a = ((e0 >> 9) & 63u) * 32u + (unsigned)(lane & 31);
                unsafeAtomicAdd(&h2[a], __builtin_bit_cast(__half2, pkb));
            }
        }
    }

    // partials (fp16, layout poff*64 + b): copy as dwords
    unsigned* wp32 = reinterpret_cast<unsigned*>(
        part + ((size_t)((prgroup * WPB + w) * NDS + dslice)) * (PR_W * B_DIM));
    const unsigned* h32 = reinterpret_cast<const unsigned*>(h2);
    #pragma unroll
    for (int k = 0; k < 32; ++k)
        wp32[k * 64 + lane] = h32[k * 64 + lane];
}

// ---------------- K4: reduce partials -> out ----------------
__global__ __launch_bounds__(256) void k_reduce(
    const __half* __restrict__ part, float* __restrict__ out) {
    const int pr = blockIdx.x;       // p-range 0..63
    const int pq = blockIdx.y;       // poff quarter 0..3
    const int t  = threadIdx.x;

    float4 acc = make_float4(0.f, 0.f, 0.f, 0.f);
    const size_t base = (size_t)pr * NDS * (PR_W * B_DIM) + (size_t)pq * 1024;
    for (int ds = 0; ds < NDS; ++ds) {
        const uint2 pv = *reinterpret_cast<const uint2*>(
            part + base + (size_t)ds * (PR_W * B_DIM) + t * 4);
        const __half2 h0 = __builtin_bit_cast(__half2, pv.x);
        const __half2 h1 = __builtin_bit_cast(__half2, pv.y);
        acc.x += __half2float(h0.x); acc.y += __half2float(h0.y);
        acc.z += __half2float(h1.x); acc.w += __half2float(h1.y);
    }

    __shared__ float st[16][65];
    const int po = (t * 4) >> 6;          // 0..15
    const int b0 = (t * 4) & 63;
    st[po][b0]     = acc.x; st[po][b0 + 1] = acc.y;
    st[po][b0 + 2] = acc.z; st[po][b0 + 3] = acc.w;
    __syncthreads();

    #pragma unroll
    for (int k = 0; k < 4; ++k) {
        const int flat = k * 256 + t;     // b*16 + po
        const int b = flat >> 4, poo = flat & 15;
        out[(size_t)b * P_DIM + pr * PR_W + pq * 16 + poo] = st[poo][b];
    }
}

// ---------------- fallback: LDS-atomic histogram ----------------
__device__ __forceinline__ float signed_val(float x, int s) {
    return __uint_as_float(__float_as_uint(x) ^ (((unsigned)(s ^ 1)) << 31));
}

__global__ __launch_bounds__(1024) void sjlt_hist_fb(
    const float* __restrict__ x, const int* __restrict__ idx,
    const int* __restrict__ sgn, float* __restrict__ out) {
    __shared__ float hist[2][P_DIM];
    for (int i = threadIdx.x; i < 2 * P_DIM; i += 1024) (&hist[0][0])[i] = 0.0f;
    __syncthreads();
    const int chunk = blockIdx.x, bg = blockIdx.y;
    const int d0 = chunk * (D_DIM / 16), b0 = bg * 2;
    const float* xr0 = x + (size_t)b0 * D_DIM + d0;
    const float* xr1 = xr0 + D_DIM;
    const int4* iv4 = reinterpret_cast<const int4*>(idx) + d0;
    const int4* sv4 = reinterpret_cast<const int4*>(sgn) + d0;
    for (int t = threadIdx.x; t < D_DIM / 16; t += 1024) {
        const int4 iv = iv4[t]; const int4 sv = sv4[t];
        const float x0 = xr0[t], x1 = xr1[t];
        unsafeAtomicAdd(&hist[0][iv.x], signed_val(x0, sv.x));
        unsafeAtomicAdd(&hist[0][iv.y], signed_val(x0, sv.y));
        unsafeAtomicAdd(&hist[0][iv.z], signed_val(x0, sv.z));
        unsafeAtomicAdd(&hist[0][iv.w], signed_val(x0, sv.w));
        unsafeAtomicAdd(&hist[1][iv.x], signed_val(x1, sv.x));
        unsafeAtomicAdd(&hist[1][iv.y], signed_val(x1, sv.y));
        unsafeAtomicAdd(&hist[1][iv.z], signed_val(x1, sv.z));
        unsafeAtomicAdd(&hist[1][iv.w], signed_val(x1, sv.w));
    }
    __syncthreads();
    float* o = out + (size_t)b0 * P_DIM;
    for (int p = threadIdx.x; p < P_DIM; p += 1024) {
        unsafeAtomicAdd(&o[p],         hist[0][p]);
        unsafeAtomicAdd(&o[P_DIM + p], hist[1][p]);
    }
}

extern "C" void kernel_launch(void* const* d_in, const int* in_sizes, int n_in,
                              void* d_out, int out_size, void* d_ws, size_t ws_size,
                              hipStream_t stream) {
    const float* x   = (const float*)d_in[0];
    const int*   idx = (const int*)d_in[1];
    const int*   sgn = (const int*)d_in[2];
    float* out = (float*)d_out;

    if (ws_size >= WS_NEED) {
        char* ws = (char*)d_ws;
        unsigned short* pk  = (unsigned short*)(ws + PK_OFF);
        unsigned short* xTb = (unsigned short*)(ws + XT_OFF);
        __half* part = (__half*)(ws + PART_OFF);

        k_pack<<<D_DIM / 256, 256, 0, stream>>>(idx, sgn, pk);
        k_transpose<<<D_DIM / TD, 256, 0, stream>>>(x, xTb);
        k_scan<<<SCAN_BLOCKS, WPB * 64, 0, stream>>>(pk, xTb, part);
        k_reduce<<<dim3(NPR, 4), 256, 0, stream>>>(part, out);
    } else {
        hipMemsetAsync(d_out, 0, (size_t)out_size * sizeof(float), stream);
        dim3 grid(16, 32);
        sjlt_hist_fb<<<grid, 1024, 0, stream>>>(x, idx, sgn, out);
    }
}

// Round 12
// 89.179 us; speedup vs baseline: 2.5757x; 2.5757x over previous
//
#include <hip/hip_runtime.h>
#include <hip/hip_bf16.h>
#include <hip/hip_fp16.h>

// SJLT projection: out[b, idx[d,c]] += x[b,d] * (2*sign[d,c]-1)
// B=64, D=262144, C=4, P=4096
//
// R12. R11 post-mortem: ds_pk_add_f16 LDS atomics = ~200cy/instr serialized
// across waves on the CU LDS unit (k_scan 198us, VALU 15%) -> REVERTED to
// R10's plain pair-RMW (69 cy chain). R10's real limit: 4 waves/SIMD can't
// hide the 69cy chain (48 of 69 issue slots used). Fix = occupancy:
//   - PR_W 64->32: hist 64->32 KB, q 12->6 KB (QCAP=48, 8 sigma)
//     => 38.7 KB/block => 4 blocks/CU = 32 waves/CU (8/SIMD, 2x R10).
//   - grid 16 prgroups x 64 dslices = 1024 = exactly 4/CU.
//   - scan redundancy doubles (cheap phase); pair-ops/wave halve.
//   - transpose: R5-R10 proven version; reduce: R11 vectorized version.

constexpr int B_DIM = 64;
constexpr int D_DIM = 262144;
constexpr int P_DIM = 4096;

constexpr int PR_W   = 32;               // p-slots per wave
constexpr int NPR    = P_DIM / PR_W;     // 128 p-ranges
constexpr int NDS    = 64;               // d-slices
constexpr int SLICE  = D_DIM / NDS;      // 4096
constexpr int WPB    = 8;                // waves per block (= pranges per block)
constexpr int SUB    = SLICE / WPB;      // 512 d scanned per wave
constexpr int SCAN_BLOCKS = (NPR / WPB) * NDS;  // 16*64 = 1024
constexpr int QCAP   = 48;               // per (target,scanner): mean 16, sd 4 -> 8 sigma

// ---- ws layout ----
constexpr size_t PK_OFF   = 0;
constexpr size_t PK_BYTES = (size_t)D_DIM * 4 * sizeof(unsigned short);          // 2 MB
constexpr size_t XT_OFF   = PK_OFF + PK_BYTES;
constexpr size_t XT_BYTES = (size_t)D_DIM * B_DIM * sizeof(unsigned short);      // 33.5 MB
constexpr size_t PART_OFF = XT_OFF + XT_BYTES;
constexpr size_t PART_BYTES = (size_t)NPR * NDS * PR_W * B_DIM * sizeof(__half); // 33.5 MB
constexpr size_t WS_NEED  = PART_OFF + PART_BYTES;                               // ~69 MB

// ---------------- K1: pack idx+sign into ushort ----------------
__global__ __launch_bounds__(256) void k_pack(
    const int* __restrict__ idx, const int* __restrict__ sgn,
    unsigned short* __restrict__ pk) {
    const int d = blockIdx.x * 256 + threadIdx.x;
    const int4 iv = reinterpret_cast<const int4*>(idx)[d];
    const int4 sv = reinterpret_cast<const int4*>(sgn)[d];
    ushort4 o;
    o.x = (unsigned short)((iv.x & 4095) | (sv.x << 15));
    o.y = (unsigned short)((iv.y & 4095) | (sv.y << 15));
    o.z = (unsigned short)((iv.z & 4095) | (sv.z << 15));
    o.w = (unsigned short)((iv.w & 4095) | (sv.w << 15));
    reinterpret_cast<ushort4*>(pk)[d] = o;
}

// ---------------- K2: transpose x[64][D] -> xTb[D][64] (bf16) ----------------
__device__ __forceinline__ unsigned short f32_to_bf16_rne(float f) {
    unsigned u = __float_as_uint(f);
    u += 0x7FFFu + ((u >> 16) & 1u);
    return (unsigned short)(u >> 16);
}

__global__ __launch_bounds__(256) void k_transpose(
    const float* __restrict__ x, unsigned short* __restrict__ xTb) {
    __shared__ float tile[64 * 65];
    const int d0 = blockIdx.x * 64;
    const int t = threadIdx.x;
    const int lane = t & 63;
    #pragma unroll
    for (int k = 0; k < 16; ++k) {
        const int b = k * 4 + (t >> 6);
        tile[lane * 65 + b] = x[(size_t)b * D_DIM + d0 + lane];
    }
    __syncthreads();
    #pragma unroll
    for (int k = 0; k < 16; ++k) {
        const int dr = k * 4 + (t >> 6);
        xTb[(size_t)(d0 + dr) * B_DIM + lane] = f32_to_bf16_rne(tile[dr * 65 + lane]);
    }
}

// ---------------- K3: 8-wave cooperative scan + scalarized paired process ---
// u16 entry: bits 0-8 = dloc (scanner-local), 9-13 = poff (0..31),
//            bit 15 = (sv ^ 1) -> negate exactly when sv==0.
__global__ __launch_bounds__(WPB * 64, 8) void k_scan(
    const unsigned short* __restrict__ pk,
    const unsigned short* __restrict__ xTb,
    __half* __restrict__ part) {
    __shared__ __half2 hist[WPB][PR_W * 32];                    // 8 x 4 KB = 32 KB
    __shared__ alignas(16) unsigned short q[WPB][WPB][QCAP];    // 6 KB
    __shared__ int qcnt[WPB][WPB];                              // 256 B

    const int w    = threadIdx.x >> 6;
    const int lane = threadIdx.x & 63;
    const int dslice  = blockIdx.x & (NDS - 1);   // stride-64 peers -> same XCD
    const int prgroup = blockIdx.x >> 6;          // 0..15
    const unsigned p0 = (unsigned)(prgroup * (WPB * PR_W));  // 256-wide p base
    const int dbase   = dslice * SLICE;

    __half2* h2 = hist[w];
    {
        unsigned* h32 = reinterpret_cast<unsigned*>(h2);
        #pragma unroll
        for (int k = 0; k < 16; ++k) h32[k * 64 + lane] = 0u;
    }

    // --- scan: wave w scans slice-local d in [w*SUB, (w+1)*SUB) ---
    const ushort4* pk4 = reinterpret_cast<const ushort4*>(pk);
    const unsigned long long lmask = (1ull << lane) - 1ull;
    int c0 = 0, c1 = 0, c2 = 0, c3 = 0, c4 = 0, c5 = 0, c6 = 0, c7 = 0;
    for (int step = 0; step < SUB / 64; ++step) {   // 8 steps
        const int dloc = step * 64 + lane;          // scanner-local (0..511)
        const ushort4 v = pk4[dbase + w * SUB + dloc];
        #pragma unroll
        for (int c = 0; c < 4; ++c) {
            const unsigned u = (c == 0) ? v.x : (c == 1) ? v.y : (c == 2) ? v.z : v.w;
            const unsigned off = (u & 4095u) - p0;            // unsigned wrap
            const bool hit = off < (unsigned)(WPB * PR_W);    // < 256
            const unsigned t = hit ? (off >> 5) : 0xFFu;      // target wave 0..7
            const unsigned long long m0 = __ballot(t == 0u);
            const unsigned long long m1 = __ballot(t == 1u);
            const unsigned long long m2 = __ballot(t == 2u);
            const unsigned long long m3 = __ballot(t == 3u);
            const unsigned long long m4 = __ballot(t == 4u);
            const unsigned long long m5 = __ballot(t == 5u);
            const unsigned long long m6 = __ballot(t == 6u);
            const unsigned long long m7 = __ballot(t == 7u);
            if (hit) {
                const unsigned long long mt =
                    t < 4u ? (t < 2u ? (t == 0u ? m0 : m1) : (t == 2u ? m2 : m3))
                           : (t < 6u ? (t == 4u ? m4 : m5) : (t == 6u ? m6 : m7));
                const int base =
                    t < 4u ? (t < 2u ? (t == 0u ? c0 : c1) : (t == 2u ? c2 : c3))
                           : (t < 6u ? (t == 4u ? c4 : c5) : (t == 6u ? c6 : c7));
                const int pos = base + __popcll(mt & lmask);
                const unsigned e16 = (unsigned)dloc | ((off & 31u) << 9)
                                   | (((u >> 15) ^ 1u) << 15);
                if (pos < QCAP) q[t][w][pos] = (unsigned short)e16;
            }
            c0 += __popcll(m0); c1 += __popcll(m1);
            c2 += __popcll(m2); c3 += __popcll(m3);
            c4 += __popcll(m4); c5 += __popcll(m5);
            c6 += __popcll(m6); c7 += __popcll(m7);
        }
    }
    if (lane == 0) {
        qcnt[0][w] = c0 < QCAP ? c0 : QCAP;
        qcnt[1][w] = c1 < QCAP ? c1 : QCAP;
        qcnt[2][w] = c2 < QCAP ? c2 : QCAP;
        qcnt[3][w] = c3 < QCAP ? c3 : QCAP;
        qcnt[4][w] = c4 < QCAP ? c4 : QCAP;
        qcnt[5][w] = c5 < QCAP ? c5 : QCAP;
        qcnt[6][w] = c6 < QCAP ? c6 : QCAP;
        qcnt[7][w] = c7 < QCAP ? c7 : QCAP;
    }
    __syncthreads();

    // --- process: wave w owns prange = prgroup*8 + w ---
    const char* xs_c = reinterpret_cast<const char*>(xTb + (size_t)dbase * B_DIM);
    const unsigned li4 = (unsigned)(lane & 31) * 4u;
    const bool hi = lane >= 32;

    // pair-op: wrd packs 2 entries (lo16 -> lanes 0-31, hi16 -> lanes 32-63);
    // dv = this lane's gathered dword (2 bf16). Plain RMW on wave-private hist.
    auto pair_rmw = [&](unsigned wrd, unsigned dv) {
        const unsigned poL = (wrd >> 9) & 31u, poH = (wrd >> 25) & 31u;
        const unsigned smL = (wrd & 0x8000u)     ? 0x80008000u : 0u;
        const unsigned smH = (wrd & 0x80000000u) ? 0x80008000u : 0u;
        const float flo = __uint_as_float(dv << 16);
        const float fhh = __uint_as_float(dv & 0xFFFF0000u);
        unsigned pkb = __builtin_bit_cast(unsigned, __floats2half2_rn(flo, fhh));
        pkb ^= hi ? smH : smL;
        const unsigned a = (hi ? poH : poL) * 32u + (unsigned)(lane & 31);
        if (poL != poH) {                       // uniform (scalar) branch
            const __half2 v2 = __builtin_bit_cast(__half2, pkb);
            h2[a] = __hadd2(h2[a], v2);
        } else {
            // rare collision: combine across halves in-register, single RMW
            // by the lo half (nothing for the compiler to merge/reorder).
            const unsigned other = (unsigned)__shfl((int)pkb, (lane & 31) + 32);
            if (!hi) {
                const __half2 vsum = __hadd2(__builtin_bit_cast(__half2, pkb),
                                             __builtin_bit_cast(__half2, other));
                h2[a] = __hadd2(h2[a], vsum);
            }
        }
    };

    for (int s = 0; s < WPB; ++s) {
        const int n = qcnt[w][s];
        const unsigned short* qs = q[w][s];
        const unsigned sb = (unsigned)(s * SUB) * 128u;   // scanner byte base
        int i = 0;
        for (; i + 8 <= n; i += 8) {            // 4 pair-ops, 4 gathers in flight
            const uint4 E = *reinterpret_cast<const uint4*>(qs + i);
            const unsigned w0 = __builtin_amdgcn_readfirstlane(E.x);
            const unsigned w1 = __builtin_amdgcn_readfirstlane(E.y);
            const unsigned w2 = __builtin_amdgcn_readfirstlane(E.z);
            const unsigned w3 = __builtin_amdgcn_readfirstlane(E.w);
            const unsigned va0 = sb + (hi ? ((w0 >> 16) & 511u) : (w0 & 511u)) * 128u + li4;
            const unsigned va1 = sb + (hi ? ((w1 >> 16) & 511u) : (w1 & 511u)) * 128u + li4;
            const unsigned va2 = sb + (hi ? ((w2 >> 16) & 511u) : (w2 & 511u)) * 128u + li4;
            const unsigned va3 = sb + (hi ? ((w3 >> 16) & 511u) : (w3 & 511u)) * 128u + li4;
            const unsigned d0 = *reinterpret_cast<const unsigned*>(xs_c + va0);
            const unsigned d1 = *reinterpret_cast<const unsigned*>(xs_c + va1);
            const unsigned d2 = *reinterpret_cast<const unsigned*>(xs_c + va2);
            const unsigned d3 = *reinterpret_cast<const unsigned*>(xs_c + va3);
            pair_rmw(w0, d0);
            pair_rmw(w1, d1);
            pair_rmw(w2, d2);
            pair_rmw(w3, d3);
        }
        for (; i + 2 <= n; i += 2) {
            const unsigned wrd = __builtin_amdgcn_readfirstlane(
                *reinterpret_cast<const unsigned*>(qs + i));
            const unsigned va = sb + (hi ? ((wrd >> 16) & 511u) : (wrd & 511u)) * 128u + li4;
            const unsigned dv = *reinterpret_cast<const unsigned*>(xs_c + va);
            pair_rmw(wrd, dv);
        }
        if (i < n) {                            // odd tail: half-wave op
            const unsigned e0 = __builtin_amdgcn_readfirstlane((unsigned)qs[i]);
            if (!hi) {
                const unsigned va = sb + (e0 & 511u) * 128u + li4;
                const unsigned dv = *reinterpret_cast<const unsigned*>(xs_c + va);
                const float flo = __uint_as_float(dv << 16);
                const float fhh = __uint_as_float(dv & 0xFFFF0000u);
                unsigned pkb = __builtin_bit_cast(unsigned, __floats2half2_rn(flo, fhh));
                pkb ^= (e0 & 0x8000u) ? 0x80008000u : 0u;
                const __half2 v2 = __builtin_bit_cast(__half2, pkb);
                const unsigned a = ((e0 >> 9) & 31u) * 32u + (unsigned)(lane & 31);
                h2[a] = __hadd2(h2[a], v2);
            }
        }
    }

    // partials (fp16, layout poff*64 + b, 1024 dwords/wave): copy as dwords
    unsigned* wp32 = reinterpret_cast<unsigned*>(
        part + ((size_t)((prgroup * WPB + w) * NDS + dslice)) * (PR_W * B_DIM));
    const unsigned* h32 = reinterpret_cast<const unsigned*>(h2);
    #pragma unroll
    for (int k = 0; k < 16; ++k)
        wp32[k * 64 + lane] = h32[k * 64 + lane];
}

// ---------------- K4: reduce partials -> out ----------------
__global__ __launch_bounds__(256) void k_reduce(
    const __half* __restrict__ part, float* __restrict__ out) {
    const int pr = blockIdx.x;       // p-range 0..127
    const int pq = blockIdx.y;       // poff half 0..1
    const int t  = threadIdx.x;

    float4 acc = make_float4(0.f, 0.f, 0.f, 0.f);
    const size_t base = (size_t)pr * NDS * (PR_W * B_DIM) + (size_t)pq * 1024;
    for (int ds = 0; ds < NDS; ++ds) {
        const uint2 pv = *reinterpret_cast<const uint2*>(
            part + base + (size_t)ds * (PR_W * B_DIM) + t * 4);
        const __half2 h0 = __builtin_bit_cast(__half2, pv.x);
        const __half2 h1 = __builtin_bit_cast(__half2, pv.y);
        acc.x += __half2float(h0.x); acc.y += __half2float(h0.y);
        acc.z += __half2float(h1.x); acc.w += __half2float(h1.y);
    }

    __shared__ float st[16][65];
    const int po = (t * 4) >> 6;          // 0..15 (local within pq half)
    const int b0 = (t * 4) & 63;
    st[po][b0]     = acc.x; st[po][b0 + 1] = acc.y;
    st[po][b0 + 2] = acc.z; st[po][b0 + 3] = acc.w;
    __syncthreads();

    #pragma unroll
    for (int k = 0; k < 4; ++k) {
        const int flat = k * 256 + t;     // b*16 + po
        const int b = flat >> 4, poo = flat & 15;
        out[(size_t)b * P_DIM + pr * PR_W + pq * 16 + poo] = st[poo][b];
    }
}

// ---------------- fallback: LDS-atomic histogram ----------------
__device__ __forceinline__ float signed_val(float x, int s) {
    return __uint_as_float(__float_as_uint(x) ^ (((unsigned)(s ^ 1)) << 31));
}

__global__ __launch_bounds__(1024) void sjlt_hist_fb(
    const float* __restrict__ x, const int* __restrict__ idx,
    const int* __restrict__ sgn, float* __restrict__ out) {
    __shared__ float hist[2][P_DIM];
    for (int i = threadIdx.x; i < 2 * P_DIM; i += 1024) (&hist[0][0])[i] = 0.0f;
    __syncthreads();
    const int chunk = blockIdx.x, bg = blockIdx.y;
    const int d0 = chunk * (D_DIM / 16), b0 = bg * 2;
    const float* xr0 = x + (size_t)b0 * D_DIM + d0;
    const float* xr1 = xr0 + D_DIM;
    const int4* iv4 = reinterpret_cast<const int4*>(idx) + d0;
    const int4* sv4 = reinterpret_cast<const int4*>(sgn) + d0;
    for (int t = threadIdx.x; t < D_DIM / 16; t += 1024) {
        const int4 iv = iv4[t]; const int4 sv = sv4[t];
        const float x0 = xr0[t], x1 = xr1[t];
        unsafeAtomicAdd(&hist[0][iv.x], signed_val(x0, sv.x));
        unsafeAtomicAdd(&hist[0][iv.y], signed_val(x0, sv.y));
        unsafeAtomicAdd(&hist[0][iv.z], signed_val(x0, sv.z));
        unsafeAtomicAdd(&hist[0][iv.w], signed_val(x0, sv.w));
        unsafeAtomicAdd(&hist[1][iv.x], signed_val(x1, sv.x));
        unsafeAtomicAdd(&hist[1][iv.y], signed_val(x1, sv.y));
        unsafeAtomicAdd(&hist[1][iv.z], signed_val(x1, sv.z));
        unsafeAtomicAdd(&hist[1][iv.w], signed_val(x1, sv.w));
    }
    __syncthreads();
    float* o = out + (size_t)b0 * P_DIM;
    for (int p = threadIdx.x; p < P_DIM; p += 1024) {
        unsafeAtomicAdd(&o[p],         hist[0][p]);
        unsafeAtomicAdd(&o[P_DIM + p], hist[1][p]);
    }
}

extern "C" void kernel_launch(void* const* d_in, const int* in_sizes, int n_in,
                              void* d_out, int out_size, void* d_ws, size_t ws_size,
                              hipStream_t stream) {
    const float* x   = (const float*)d_in[0];
    const int*   idx = (const int*)d_in[1];
    const int*   sgn = (const int*)d_in[2];
    float* out = (float*)d_out;

    if (ws_size >= WS_NEED) {
        char* ws = (char*)d_ws;
        unsigned short* pk  = (unsigned short*)(ws + PK_OFF);
        unsigned short* xTb = (unsigned short*)(ws + XT_OFF);
        __half* part = (__half*)(ws + PART_OFF);

        k_pack<<<D_DIM / 256, 256, 0, stream>>>(idx, sgn, pk);
        k_transpose<<<D_DIM / 64, 256, 0, stream>>>(x, xTb);
        k_scan<<<SCAN_BLOCKS, WPB * 64, 0, stream>>>(pk, xTb, part);
        k_reduce<<<dim3(NPR, 2), 256, 0, stream>>>(part, out);
    } else {
        hipMemsetAsync(d_out, 0, (size_t)out_size * sizeof(float), stream);
        dim3 grid(16, 32);
        sjlt_hist_fb<<<grid, 1024, 0, stream>>>(x, idx, sgn, out);
    }
}

// Round 13
// 76.569 us; speedup vs baseline: 2.9999x; 1.1647x over previous
//
#include <hip/hip_runtime.h>
#include <hip/hip_bf16.h>
#include <hip/hip_fp16.h>

// SJLT projection: out[b, idx[d,c]] += x[b,d] * (2*sign[d,c]-1)
// B=64, D=262144, C=4, P=4096
//
// R13. R12 post-mortem: k_scan 62us VALU-bound, ~2/3 of it the 16x-redundant
// scan (every prgroup rescans the slice). Redesign: one-pass global binning.
//   K1 k_binpack: scan all 1M entries ONCE; ballot-bin (deterministic rank)
//      into [dslice=64][scanner=16][bin=16] global regions (u32 entries,
//      cap 128 = 8.2 sigma) + counts. ~6us instead of 16x-redundant scan.
//   K2 k_transpose: x -> bf16 xT[D][64] (unchanged, BW floor).
//   K3 k_process: block=(bin,dslice)=1024=exactly 4/CU (LDS 40KB: u16
//      queues QCAP=28=7sigma). Tiny re-bin (~2 c-iters) then R12's proven
//      scalarized pair-RMW on wave-private f16x2 hist. 8 waves/SIMD.
//   K4 k_reduce: partials -> out (R12 verbatim).
// No atomics anywhere; fully deterministic (fixed regions + ballot ranks).

constexpr int B_DIM = 64;
constexpr int D_DIM = 262144;
constexpr int P_DIM = 4096;

constexpr int NDS   = 64;
constexpr int SLICE = D_DIM / NDS;      // 4096 d per dslice
constexpr int NBIN  = 16;               // p-bins of 256
constexpr int NSC   = 16;               // scanners per dslice
constexpr int SC_D  = SLICE / NSC;      // 256 d per scanner
constexpr int BCAP  = 128;              // entries per (dslice,sc,bin): mean 64, 8.2 sigma
constexpr int WPB   = 8;
constexpr int PR_W  = 32;
constexpr int NPR   = P_DIM / PR_W;     // 128
constexpr int QCAP_E = 28;              // u16 entries per (target,sc): mean 8, 7.1 sigma

// ---- ws layout ----
constexpr size_t REG_OFF   = 0;
constexpr size_t REG_BYTES = (size_t)NDS * NSC * NBIN * BCAP * 4;          // 8.4 MB
constexpr size_t CNT_OFF   = REG_OFF + REG_BYTES;
constexpr size_t CNT_BYTES = (size_t)NDS * NSC * NBIN * 4;                 // 64 KB
constexpr size_t XT_OFF    = CNT_OFF + CNT_BYTES;
constexpr size_t XT_BYTES  = (size_t)D_DIM * B_DIM * 2;                    // 33.5 MB
constexpr size_t PART_OFF  = XT_OFF + XT_BYTES;
constexpr size_t PART_BYTES = (size_t)NPR * NDS * PR_W * B_DIM * 2;        // 33.5 MB
constexpr size_t WS_NEED   = PART_OFF + PART_BYTES;                        // ~76 MB

// ---------------- K1: one-pass pack + bin ----------------
// entry u32: bits 0-18 rowbyte (dloc*128, dloc in slice), 19-26 p&255,
//            bit 31 = (sv^1) -> negate when set.
__global__ __launch_bounds__(512) void k_binpack(
    const int* __restrict__ idx, const int* __restrict__ sgn,
    unsigned* __restrict__ reg, int* __restrict__ cnt) {
    const int w = threadIdx.x >> 6, lane = threadIdx.x & 63;
    const int dslice = blockIdx.x >> 1;
    const int half   = blockIdx.x & 1;
    const int sc     = half * 8 + w;
    const int d0     = dslice * SLICE + sc * SC_D;
    unsigned* regw = reg + ((size_t)(dslice * NSC + sc) * NBIN) * BCAP;
    const unsigned long long lmask = (1ull << lane) - 1ull;

    unsigned cb[16];
    #pragma unroll
    for (int b = 0; b < 16; ++b) cb[b] = 0;

    #pragma unroll
    for (int step = 0; step < SC_D / 64; ++step) {     // 4 steps
        const int dli = step * 64 + lane;
        const int4 iv = reinterpret_cast<const int4*>(idx)[d0 + dli];
        const int4 sv = reinterpret_cast<const int4*>(sgn)[d0 + dli];
        const unsigned rowbyte = (unsigned)((sc * SC_D + dli) << 7);
        #pragma unroll
        for (int c = 0; c < 4; ++c) {
            const unsigned p = ((unsigned)((c==0)?iv.x:(c==1)?iv.y:(c==2)?iv.z:iv.w)) & 4095u;
            const unsigned s = ((unsigned)((c==0)?sv.x:(c==1)?sv.y:(c==2)?sv.z:sv.w)) & 1u;
            const unsigned e = rowbyte | ((p & 255u) << 19) | ((s ^ 1u) << 31);
            const unsigned bin = p >> 8;
            unsigned pos = 0;
            #pragma unroll
            for (int b = 0; b < 16; ++b) {
                const unsigned long long m = __ballot(bin == (unsigned)b);
                if (bin == (unsigned)b) pos = cb[b] + (unsigned)__popcll(m & lmask);
                cb[b] += (unsigned)__popcll(m);
            }
            if (pos < (unsigned)BCAP) regw[bin * BCAP + pos] = e;
        }
    }
    unsigned cval = 0;
    #pragma unroll
    for (int b = 0; b < 16; ++b) {
        const unsigned cc = cb[b] < (unsigned)BCAP ? cb[b] : (unsigned)BCAP;
        cval = (lane == b) ? cc : cval;
    }
    if (lane < 16) cnt[(dslice * NSC + sc) * NBIN + lane] = (int)cval;
}

// ---------------- K2: transpose x[64][D] -> xTb[D][64] (bf16) ----------------
__device__ __forceinline__ unsigned short f32_to_bf16_rne(float f) {
    unsigned u = __float_as_uint(f);
    u += 0x7FFFu + ((u >> 16) & 1u);
    return (unsigned short)(u >> 16);
}

__global__ __launch_bounds__(256) void k_transpose(
    const float* __restrict__ x, unsigned short* __restrict__ xTb) {
    __shared__ float tile[64 * 65];
    const int d0 = blockIdx.x * 64;
    const int t = threadIdx.x;
    const int lane = t & 63;
    #pragma unroll
    for (int k = 0; k < 16; ++k) {
        const int b = k * 4 + (t >> 6);
        tile[lane * 65 + b] = x[(size_t)b * D_DIM + d0 + lane];
    }
    __syncthreads();
    #pragma unroll
    for (int k = 0; k < 16; ++k) {
        const int dr = k * 4 + (t >> 6);
        xTb[(size_t)(d0 + dr) * B_DIM + lane] = f32_to_bf16_rne(tile[dr * 65 + lane]);
    }
}

// ---------------- K3: re-bin + scalarized paired process ----------------
// u16 queue entry: bits 0-7 dloc within scanner (0..255), 8-12 poff (0..31),
//                  bit 15 = negate.
__global__ __launch_bounds__(512, 8) void k_process(
    const unsigned* __restrict__ reg, const int* __restrict__ cnt,
    const unsigned short* __restrict__ xTb, __half* __restrict__ part) {
    __shared__ __half2 hist[WPB][PR_W * 32];              // 32 KB
    __shared__ unsigned short q[WPB][NSC][QCAP_E];        // 7 KB (rows 56B, dword-aligned)
    __shared__ short qcnt[WPB][NSC];                      // 256 B

    const int w = threadIdx.x >> 6, lane = threadIdx.x & 63;
    const int dslice = blockIdx.x & 63;     // stride-64 peers share xTb slice/XCD
    const int bin    = blockIdx.x >> 6;     // 0..15

    __half2* h2 = hist[w];
    {
        unsigned* h32 = reinterpret_cast<unsigned*>(h2);
        #pragma unroll
        for (int k = 0; k < 16; ++k) h32[k * 64 + lane] = 0u;
    }

    const unsigned long long lmask = (1ull << lane) - 1ull;

    // --- re-bin: wave w handles scanners 2w, 2w+1 ---
    #pragma unroll
    for (int h = 0; h < 2; ++h) {
        const int sc = 2 * w + h;
        const int n  = cnt[(dslice * NSC + sc) * NBIN + bin];
        const unsigned* list = reg + ((size_t)((dslice * NSC + sc) * NBIN + bin)) * BCAP;
        unsigned qc[8];
        #pragma unroll
        for (int b = 0; b < 8; ++b) qc[b] = 0;
        for (int base = 0; base < n; base += 64) {
            const int i = base + lane;
            const bool valid = i < n;
            const unsigned e = valid ? list[i] : 0u;
            const unsigned t = valid ? ((e >> 24) & 7u) : 8u;
            const unsigned e16 = ((e >> 7) & 255u) | (((e >> 19) & 31u) << 8)
                               | ((e >> 31) << 15);
            unsigned pos = 0;
            #pragma unroll
            for (int b = 0; b < 8; ++b) {
                const unsigned long long m = __ballot(t == (unsigned)b);
                if (t == (unsigned)b) pos = qc[b] + (unsigned)__popcll(m & lmask);
                qc[b] += (unsigned)__popcll(m);
            }
            if (valid && pos < (unsigned)QCAP_E)
                q[t][sc][pos] = (unsigned short)e16;
        }
        unsigned cval = 0;
        #pragma unroll
        for (int b = 0; b < 8; ++b) {
            const unsigned cc = qc[b] < (unsigned)QCAP_E ? qc[b] : (unsigned)QCAP_E;
            cval = (lane == b) ? cc : cval;
        }
        if (lane < 8) qcnt[lane][sc] = (short)cval;
    }
    __syncthreads();

    // --- process: wave w owns prange = bin*8 + w ---
    const char* xs_c = reinterpret_cast<const char*>(xTb) + (size_t)dslice * SLICE * 128;
    const unsigned li4 = (unsigned)(lane & 31) * 4u;
    const bool hi = lane >= 32;

    auto pair_rmw = [&](unsigned wrd, unsigned dv) {
        const unsigned poL = (wrd >> 8) & 31u, poH = (wrd >> 24) & 31u;
        const unsigned smL = (wrd & 0x8000u)     ? 0x80008000u : 0u;
        const unsigned smH = (wrd & 0x80000000u) ? 0x80008000u : 0u;
        const float flo = __uint_as_float(dv << 16);
        const float fhh = __uint_as_float(dv & 0xFFFF0000u);
        unsigned pkb = __builtin_bit_cast(unsigned, __floats2half2_rn(flo, fhh));
        pkb ^= hi ? smH : smL;
        const unsigned a = (hi ? poH : poL) * 32u + (unsigned)(lane & 31);
        if (poL != poH) {                       // uniform (scalar) branch
            const __half2 v2 = __builtin_bit_cast(__half2, pkb);
            h2[a] = __hadd2(h2[a], v2);
        } else {
            // rare collision: combine across halves in-register; lo half RMWs.
            const unsigned other = (unsigned)__shfl((int)pkb, (lane & 31) + 32);
            if (!hi) {
                const __half2 vsum = __hadd2(__builtin_bit_cast(__half2, pkb),
                                             __builtin_bit_cast(__half2, other));
                h2[a] = __hadd2(h2[a], vsum);
            }
        }
    };

    for (int s = 0; s < NSC; ++s) {
        const int n = qcnt[w][s];
        const unsigned* qs32 = reinterpret_cast<const unsigned*>(&q[w][s][0]);
        const unsigned sb = (unsigned)s << 15;   // s * 256 rows * 128 B
        int i = 0;
        for (; i + 4 <= n; i += 4) {             // 2 pair-ops, 2 gathers in flight
            const unsigned wa = __builtin_amdgcn_readfirstlane(qs32[i >> 1]);
            const unsigned wb = __builtin_amdgcn_readfirstlane(qs32[(i >> 1) + 1]);
            const unsigned vaA = sb + ((hi ? (wa >> 16) : wa) & 255u) * 128u + li4;
            const unsigned vaB = sb + ((hi ? (wb >> 16) : wb) & 255u) * 128u + li4;
            const unsigned dA = *reinterpret_cast<const unsigned*>(xs_c + vaA);
            const unsigned dB = *reinterpret_cast<const unsigned*>(xs_c + vaB);
            pair_rmw(wa, dA);
            pair_rmw(wb, dB);
        }
        for (; i + 2 <= n; i += 2) {
            const unsigned wa = __builtin_amdgcn_readfirstlane(qs32[i >> 1]);
            const unsigned va = sb + ((hi ? (wa >> 16) : wa) & 255u) * 128u + li4;
            pair_rmw(wa, *reinterpret_cast<const unsigned*>(xs_c + va));
        }
        if (i < n) {                             // odd tail: half-wave op
            const unsigned e0 = __builtin_amdgcn_readfirstlane((unsigned)q[w][s][i]);
            if (!hi) {
                const unsigned va = sb + (e0 & 255u) * 128u + li4;
                const unsigned dv = *reinterpret_cast<const unsigned*>(xs_c + va);
                const float flo = __uint_as_float(dv << 16);
                const float fhh = __uint_as_float(dv & 0xFFFF0000u);
                unsigned pkb = __builtin_bit_cast(unsigned, __floats2half2_rn(flo, fhh));
                pkb ^= (e0 & 0x8000u) ? 0x80008000u : 0u;
                const __half2 v2 = __builtin_bit_cast(__half2, pkb);
                const unsigned a = ((e0 >> 8) & 31u) * 32u + (unsigned)(lane & 31);
                h2[a] = __hadd2(h2[a], v2);
            }
        }
    }

    // partials (fp16, layout poff*64 + b, 1024 dwords/wave)
    unsigned* wp32 = reinterpret_cast<unsigned*>(
        part + ((size_t)((bin * WPB + w) * NDS + dslice)) * (PR_W * B_DIM));
    const unsigned* h32 = reinterpret_cast<const unsigned*>(h2);
    #pragma unroll
    for (int k = 0; k < 16; ++k)
        wp32[k * 64 + lane] = h32[k * 64 + lane];
}

// ---------------- K4: reduce partials -> out ----------------
__global__ __launch_bounds__(256) void k_reduce(
    const __half* __restrict__ part, float* __restrict__ out) {
    const int pr = blockIdx.x;       // p-range 0..127
    const int pq = blockIdx.y;       // poff half 0..1
    const int t  = threadIdx.x;

    float4 acc = make_float4(0.f, 0.f, 0.f, 0.f);
    const size_t base = (size_t)pr * NDS * (PR_W * B_DIM) + (size_t)pq * 1024;
    for (int ds = 0; ds < NDS; ++ds) {
        const uint2 pv = *reinterpret_cast<const uint2*>(
            part + base + (size_t)ds * (PR_W * B_DIM) + t * 4);
        const __half2 h0 = __builtin_bit_cast(__half2, pv.x);
        const __half2 h1 = __builtin_bit_cast(__half2, pv.y);
        acc.x += __half2float(h0.x); acc.y += __half2float(h0.y);
        acc.z += __half2float(h1.x); acc.w += __half2float(h1.y);
    }

    __shared__ float st[16][65];
    const int po = (t * 4) >> 6;
    const int b0 = (t * 4) & 63;
    st[po][b0]     = acc.x; st[po][b0 + 1] = acc.y;
    st[po][b0 + 2] = acc.z; st[po][b0 + 3] = acc.w;
    __syncthreads();

    #pragma unroll
    for (int k = 0; k < 4; ++k) {
        const int flat = k * 256 + t;     // b*16 + po
        const int b = flat >> 4, poo = flat & 15;
        out[(size_t)b * P_DIM + pr * PR_W + pq * 16 + poo] = st[poo][b];
    }
}

// ---------------- fallback: LDS-atomic histogram ----------------
__device__ __forceinline__ float signed_val(float x, int s) {
    return __uint_as_float(__float_as_uint(x) ^ (((unsigned)(s ^ 1)) << 31));
}

__global__ __launch_bounds__(1024) void sjlt_hist_fb(
    const float* __restrict__ x, const int* __restrict__ idx,
    const int* __restrict__ sgn, float* __restrict__ out) {
    __shared__ float hist[2][P_DIM];
    for (int i = threadIdx.x; i < 2 * P_DIM; i += 1024) (&hist[0][0])[i] = 0.0f;
    __syncthreads();
    const int chunk = blockIdx.x, bg = blockIdx.y;
    const int d0 = chunk * (D_DIM / 16), b0 = bg * 2;
    const float* xr0 = x + (size_t)b0 * D_DIM + d0;
    const float* xr1 = xr0 + D_DIM;
    const int4* iv4 = reinterpret_cast<const int4*>(idx) + d0;
    const int4* sv4 = reinterpret_cast<const int4*>(sgn) + d0;
    for (int t = threadIdx.x; t < D_DIM / 16; t += 1024) {
        const int4 iv = iv4[t]; const int4 sv = sv4[t];
        const float x0 = xr0[t], x1 = xr1[t];
        unsafeAtomicAdd(&hist[0][iv.x], signed_val(x0, sv.x));
        unsafeAtomicAdd(&hist[0][iv.y], signed_val(x0, sv.y));
        unsafeAtomicAdd(&hist[0][iv.z], signed_val(x0, sv.z));
        unsafeAtomicAdd(&hist[0][iv.w], signed_val(x0, sv.w));
        unsafeAtomicAdd(&hist[1][iv.x], signed_val(x1, sv.x));
        unsafeAtomicAdd(&hist[1][iv.y], signed_val(x1, sv.y));
        unsafeAtomicAdd(&hist[1][iv.z], signed_val(x1, sv.z));
        unsafeAtomicAdd(&hist[1][iv.w], signed_val(x1, sv.w));
    }
    __syncthreads();
    float* o = out + (size_t)b0 * P_DIM;
    for (int p = threadIdx.x; p < P_DIM; p += 1024) {
        unsafeAtomicAdd(&o[p],         hist[0][p]);
        unsafeAtomicAdd(&o[P_DIM + p], hist[1][p]);
    }
}

extern "C" void kernel_launch(void* const* d_in, const int* in_sizes, int n_in,
                              void* d_out, int out_size, void* d_ws, size_t ws_size,
                              hipStream_t stream) {
    const float* x   = (const float*)d_in[0];
    const int*   idx = (const int*)d_in[1];
    const int*   sgn = (const int*)d_in[2];
    float* out = (float*)d_out;

    if (ws_size >= WS_NEED) {
        char* ws = (char*)d_ws;
        unsigned* reg = (unsigned*)(ws + REG_OFF);
        int* cnt      = (int*)(ws + CNT_OFF);
        unsigned short* xTb = (unsigned short*)(ws + XT_OFF);
        __half* part  = (__half*)(ws + PART_OFF);

        k_binpack<<<NDS * 2, 512, 0, stream>>>(idx, sgn, reg, cnt);
        k_transpose<<<D_DIM / 64, 256, 0, stream>>>(x, xTb);
        k_process<<<NBIN * NDS, 512, 0, stream>>>(reg, cnt, xTb, part);
        k_reduce<<<dim3(NPR, 2), 256, 0, stream>>>(part, out);
    } else {
        hipMemsetAsync(d_out, 0, (size_t)out_size * sizeof(float), stream);
        dim3 grid(16, 32);
        sjlt_hist_fb<<<grid, 1024, 0, stream>>>(x, idx, sgn, out);
    }
}